// Round 8
// baseline (94.672 us; speedup 1.0000x reference)
//
#include <hip/hip_runtime.h>

// Problem dims (fixed by reference setup_inputs)
#define BDIM 256
#define IDIM 1024
#define ODIM 1024

#define NW 8                  // waves per block, each owns an i-eighth
#define TILE_OL 2             // output columns per lane
#define TILE_O (64 * TILE_OL) // 128 outputs per block
#define TILE_B 2              // batch rows per thread (was 4: halved for TLP)
#define QLEN (IDIM / NW)      // 128 i per wave
#define CHUNK 8               // i per w-prefetch chunk
#define NCHUNK (QLEN / CHUNK) // 16 chunks

typedef float v2f __attribute__((ext_vector_type(2)));
typedef float v4f __attribute__((ext_vector_type(4)));

#if __has_builtin(__builtin_amdgcn_exp2f)
#define FAST_EXP2(v) __builtin_amdgcn_exp2f(v)
#else
#define FAST_EXP2(v) exp2f(v)
#endif

__global__ __launch_bounds__(512, 6)
void stl_kernel(const float* __restrict__ x,
                const float* __restrict__ w,
                const float* __restrict__ bias,
                float* __restrict__ out) {
  __shared__ float xs[TILE_B][IDIM];    // 8 KB: 2 x rows, prescaled by log2e
  __shared__ float ps[NW][64][8];       // 16 KB: per-wave partials (2o x 2b x n,d)

  const int tx = threadIdx.x;           // 0..63 -> output column (lane)
  const int ty = threadIdx.y;           // 0..7  -> i-eighth (one wave each)
  const int tid = ty * 64 + tx;
  const int o0 = blockIdx.x * TILE_O;
  const int b0 = blockIdx.y * TILE_B;

  const float LOG2E = 1.4426950408889634f;  // folds 1/TEMPERATURE too

  // ---- Stage 2 x rows once (coalesced, prescaled). Barrier #1. ----
  {
    int row = tid >> 8;                 // 256 float4 per row, 512 total
    int col = tid & 255;
    float4 v = ((const float4*)(x + (size_t)(b0 + row) * IDIM))[col];
    v.x *= LOG2E; v.y *= LOG2E; v.z *= LOG2E; v.w *= LOG2E;
    ((float4*)(&xs[row][0]))[col] = v;
  }
  __syncthreads();

  const int qbase = ty * QLEN;
  // Lane owns columns o0+tx and o0+tx+64 (+64 is a 256B immediate).
  const float* wp = w + (size_t)qbase * ODIM + o0 + tx;

  // Accumulators: [o-set][batch row], packed over i-pairs -> all v_pk_*.
  v2f an[TILE_OL][TILE_B], ad[TILE_OL][TILE_B];
#pragma unroll
  for (int s = 0; s < TILE_OL; ++s)
#pragma unroll
    for (int r = 0; r < TILE_B; ++r) { an[s][r] = (v2f){0.f, 0.f}; ad[s][r] = (v2f){0.f, 0.f}; }

  // Depth-1 A/B w double buffer (the only variant that never spilled).
  v2f wA0[CHUNK / 2], wA1[CHUNK / 2], wB0[CHUNK / 2], wB1[CHUNK / 2];

#define WLOADF(d0_, d1_, cc)                                              \
  {                                                                       \
    const float* wq = wp + (size_t)((cc) * CHUNK) * ODIM;                 \
    _Pragma("unroll")                                                     \
    for (int u = 0; u < CHUNK / 2; ++u) {                                 \
      d0_[u].x = wq[(size_t)(2 * u) * ODIM];                              \
      d0_[u].y = wq[(size_t)(2 * u + 1) * ODIM];                          \
      d1_[u].x = wq[(size_t)(2 * u) * ODIM + 64];                         \
      d1_[u].y = wq[(size_t)(2 * u + 1) * ODIM + 64];                     \
    }                                                                     \
  }

#define ROWPF(acc_n, acc_d, xpair, wpair)                                 \
  {                                                                       \
    v2f p = (xpair) * (wpair);          /* v_pk_mul (p = log2e*z) */      \
    v2f t;                                                                \
    t.x = FAST_EXP2(__builtin_fabsf(p.x));  /* v_exp_f32, abs folded */   \
    t.y = FAST_EXP2(__builtin_fabsf(p.y));                                \
    acc_n += p * t;                     /* v_pk_fma */                    \
    acc_d += t;                         /* v_pk_add */                    \
  }

#define LOF(xq) __builtin_shufflevector(xq, xq, 0, 1)
#define HIF(xq) __builtin_shufflevector(xq, xq, 2, 3)

#define COMPUTEF(wc0, wc1, cc)                                            \
  {                                                                       \
    const int jb = qbase + (cc) * CHUNK;                                  \
    _Pragma("unroll")                                                     \
    for (int h = 0; h < 2; ++h) {                                         \
      v4f xq[TILE_B];                                                     \
      _Pragma("unroll")                                                   \
      for (int r = 0; r < TILE_B; ++r)                                    \
        xq[r] = *(const v4f*)(&xs[r][jb + h * 4]);                        \
      _Pragma("unroll")                                                   \
      for (int r = 0; r < TILE_B; ++r) {                                  \
        ROWPF(an[0][r], ad[0][r], LOF(xq[r]), wc0[h * 2])                 \
        ROWPF(an[0][r], ad[0][r], HIF(xq[r]), wc0[h * 2 + 1])             \
        ROWPF(an[1][r], ad[1][r], LOF(xq[r]), wc1[h * 2])                 \
        ROWPF(an[1][r], ad[1][r], HIF(xq[r]), wc1[h * 2 + 1])             \
      }                                                                   \
    }                                                                     \
  }

  // ---- Main loop: depth-1 software pipeline, natural chunk order. ----
  WLOADF(wA0, wA1, 0)
  for (int c = 0; c < NCHUNK; c += 2) {
    WLOADF(wB0, wB1, c + 1)
    COMPUTEF(wA0, wA1, c)
    WLOADF(wA0, wA1, (c + 2) & (NCHUNK - 1))   // wrap: one harmless reload
    COMPUTEF(wB0, wB1, c + 1)
  }

  // ---- Cross-wave combine (barrier #2) ----
  // Layout per (wave, lane): [n(s0b0), n(s0b1), n(s1b0), n(s1b1),
  //                           d(s0b0), d(s0b1), d(s1b0), d(s1b1)]
  *(float4*)(&ps[ty][tx][0]) =
      make_float4(an[0][0].x + an[0][0].y, an[0][1].x + an[0][1].y,
                  an[1][0].x + an[1][0].y, an[1][1].x + an[1][1].y);
  *(float4*)(&ps[ty][tx][4]) =
      make_float4(ad[0][0].x + ad[0][0].y, ad[0][1].x + ad[0][1].y,
                  ad[1][0].x + ad[1][0].y, ad[1][1].x + ad[1][1].y);
  __syncthreads();

  // 256 outputs (2 b x 128 o); threads 0..255 take one each.
  if (tid < 256) {
    const int txp = tid & 63;           // o lane
    const int s = (tid >> 6) & 1;       // o set (0: +0, 1: +64)
    const int bq = tid >> 7;            // batch row 0/1
    float n = 0.f, d = 0.f;
#pragma unroll
    for (int wv = 0; wv < NW; ++wv) {
      n += ps[wv][txp][s * 2 + bq];
      d += ps[wv][txp][4 + s * 2 + bq];
    }
    const float LN2 = 0.6931471805599453f;
    const float scale = (float)IDIM * LN2;    // undo log2e, apply n=IDIM
    const int o = o0 + s * 64 + txp;
    out[(size_t)(b0 + bq) * ODIM + o] = scale * n / d + bias[o];
  }
}

extern "C" void kernel_launch(void* const* d_in, const int* in_sizes, int n_in,
                              void* d_out, int out_size, void* d_ws, size_t ws_size,
                              hipStream_t stream) {
  const float* x = (const float*)d_in[0];    // [256,1024] f32
  const float* w = (const float*)d_in[1];    // [1024,1024] f32
  const float* b = (const float*)d_in[2];    // [1024] f32
  float* out = (float*)d_out;                // [256,1024] f32

  dim3 grid(ODIM / TILE_O, BDIM / TILE_B);   // (8, 128) = 1024 blocks = 4/CU
  dim3 block(64, NW);                        // 512 threads = 8 waves
  stl_kernel<<<grid, block, 0, stream>>>(x, w, b, out);
}

// Round 10
// 94.167 us; speedup vs baseline: 1.0054x; 1.0054x over previous
//
#include <hip/hip_runtime.h>

// Problem dims (fixed by reference setup_inputs)
#define BDIM 256
#define IDIM 1024
#define ODIM 1024

#define NW 8                  // waves per block, each owns an i-eighth
#define OL 4                  // contiguous output columns per lane (dwordx4!)
#define TILE_O (64 * OL)      // 256 outputs per block
#define TILE_B 2              // batch rows per thread
#define QLEN (IDIM / NW)      // 128 i per wave
#define CHUNK 4               // i per w-prefetch chunk (4 x dwordx4)
#define NCHUNK (QLEN / CHUNK) // 32 chunks

typedef float v2f __attribute__((ext_vector_type(2)));
typedef float v4f __attribute__((ext_vector_type(4)));

#if __has_builtin(__builtin_amdgcn_exp2f)
#define FAST_EXP2(v) __builtin_amdgcn_exp2f(v)
#else
#define FAST_EXP2(v) exp2f(v)
#endif

__global__ __launch_bounds__(512, 4)
void stl_kernel(const float* __restrict__ x,
                const float* __restrict__ w,
                const float* __restrict__ bias,
                float* __restrict__ out) {
  __shared__ float xs[TILE_B][IDIM];    // 8 KB: 2 x rows, prescaled by log2e
  __shared__ float ps[NW][16][68];      // ~34 KB: [wave][slot][lane], stride-68
                                        // floats -> conflict-free writes

  const int tx = threadIdx.x;           // 0..63 -> o-quad (lane)
  const int ty = threadIdx.y;           // 0..7  -> i-eighth (one wave each)
  const int tid = ty * 64 + tx;
  const int o0 = blockIdx.x * TILE_O;
  const int b0 = blockIdx.y * TILE_B;

  const float LOG2E = 1.4426950408889634f;  // folds 1/TEMPERATURE too

  // ---- Stage 2 x rows once (coalesced, prescaled). Barrier #1. ----
  {
    int row = tid >> 8;                 // 256 float4 per row, 512 total
    int col = tid & 255;
    float4 v = ((const float4*)(x + (size_t)(b0 + row) * IDIM))[col];
    v.x *= LOG2E; v.y *= LOG2E; v.z *= LOG2E; v.w *= LOG2E;
    ((float4*)(&xs[row][0]))[col] = v;
  }
  __syncthreads();

  const int qbase = ty * QLEN;
  // Lane owns 4 CONTIGUOUS columns o0+4*tx..+3: one dwordx4 per (i) fetches
  // all of them -> 4x fewer VMEM instructions than scalar-dword (TA unclog).
  const float* wp = w + (size_t)qbase * ODIM + o0 + 4 * tx;

  // Accumulators: [o-pair (lo/hi of the quad)][batch row], pk over o.
  v2f an[2][TILE_B], ad[2][TILE_B];
#pragma unroll
  for (int s = 0; s < 2; ++s)
#pragma unroll
    for (int r = 0; r < TILE_B; ++r) { an[s][r] = (v2f){0.f, 0.f}; ad[s][r] = (v2f){0.f, 0.f}; }

  // w double buffer: 4 x dwordx4 per chunk (i = 4 consecutive rows).
  v4f wA[CHUNK], wB[CHUNK];

#define WLOADQ(dst, cc)                                                   \
  {                                                                       \
    const float* wq = wp + (size_t)((cc) * CHUNK) * ODIM;                 \
    _Pragma("unroll")                                                     \
    for (int u = 0; u < CHUNK; ++u)                                       \
      dst[u] = *(const v4f*)(wq + (size_t)u * ODIM);                      \
  }

  // One (i, b) step against one o-pair: x broadcast, w pair straight from
  // the loaded dwordx4 halves. exp scalar with abs folded.
#define ROWPQ(acc_n, acc_d, xx, wpair)                                    \
  {                                                                       \
    v2f p = (xx) * (wpair);             /* v_pk_mul (p = log2e*z) */      \
    v2f t;                                                                \
    t.x = FAST_EXP2(__builtin_fabsf(p.x));                                \
    t.y = FAST_EXP2(__builtin_fabsf(p.y));                                \
    acc_n += p * t;                     /* v_pk_fma */                    \
    acc_d += t;                         /* v_pk_add */                    \
  }

#define LOQ(q) __builtin_shufflevector(q, q, 0, 1)
#define HIQ(q) __builtin_shufflevector(q, q, 2, 3)

  // One i-step with LITERAL index ii (shufflevector needs parse-time consts).
#define STEPQ(wc, xq0, xq1, ii)                                           \
  {                                                                       \
    v2f wlo = LOQ(wc[ii]), whi = HIQ(wc[ii]);                             \
    v2f x0 = __builtin_shufflevector(xq0, xq0, ii, ii);                   \
    v2f x1 = __builtin_shufflevector(xq1, xq1, ii, ii);                   \
    ROWPQ(an[0][0], ad[0][0], x0, wlo)                                    \
    ROWPQ(an[1][0], ad[1][0], x0, whi)                                    \
    ROWPQ(an[0][1], ad[0][1], x1, wlo)                                    \
    ROWPQ(an[1][1], ad[1][1], x1, whi)                                    \
  }

#define COMPUTEQ(wc, cc)                                                  \
  {                                                                       \
    const int jb = qbase + (cc) * CHUNK;                                  \
    v4f xq0 = *(const v4f*)(&xs[0][jb]);   /* broadcast ds_read_b128 */   \
    v4f xq1 = *(const v4f*)(&xs[1][jb]);                                  \
    STEPQ(wc, xq0, xq1, 0)                                                \
    STEPQ(wc, xq0, xq1, 1)                                                \
    STEPQ(wc, xq0, xq1, 2)                                                \
    STEPQ(wc, xq0, xq1, 3)                                                \
  }

  // ---- Main loop: depth-1 A/B pipeline, 4 VMEM insts per chunk. ----
  WLOADQ(wA, 0)
  for (int c = 0; c < NCHUNK; c += 2) {
    WLOADQ(wB, c + 1)
    COMPUTEQ(wA, c)
    WLOADQ(wA, (c + 2) & (NCHUNK - 1))   // wrap: one harmless reload
    COMPUTEQ(wB, c + 1)
  }

  // ---- Cross-wave combine (barrier #2) ----
  // slots: b*8 + k (k=0..3: num for o=4tx+k), b*8+4+k: den.
  // Writes ps[ty][slot][tx]: lane-consecutive -> conflict-free.
#pragma unroll
  for (int bq = 0; bq < TILE_B; ++bq) {
    ps[ty][bq * 8 + 0][tx] = an[0][bq].x;
    ps[ty][bq * 8 + 1][tx] = an[0][bq].y;
    ps[ty][bq * 8 + 2][tx] = an[1][bq].x;
    ps[ty][bq * 8 + 3][tx] = an[1][bq].y;
    ps[ty][bq * 8 + 4][tx] = ad[0][bq].x;
    ps[ty][bq * 8 + 5][tx] = ad[0][bq].y;
    ps[ty][bq * 8 + 6][tx] = ad[1][bq].x;
    ps[ty][bq * 8 + 7][tx] = ad[1][bq].y;
  }
  __syncthreads();

  // 512 outputs (2 b x 256 o); each of the 512 threads takes one.
  {
    const int o_rel = tid & 255;         // 0..255
    const int bq = tid >> 8;             // 0/1
    const int t = o_rel >> 2;            // owning lane
    const int k = o_rel & 3;             // quad index
    float n = 0.f, d = 0.f;
#pragma unroll
    for (int wv = 0; wv < NW; ++wv) {
      n += ps[wv][bq * 8 + k][t];
      d += ps[wv][bq * 8 + 4 + k][t];
    }
    const float LN2 = 0.6931471805599453f;
    const float scale = (float)IDIM * LN2;    // undo log2e, apply n=IDIM
    const int o = o0 + o_rel;
    out[(size_t)(b0 + bq) * ODIM + o] = scale * n / d + bias[o];
  }
}

extern "C" void kernel_launch(void* const* d_in, const int* in_sizes, int n_in,
                              void* d_out, int out_size, void* d_ws, size_t ws_size,
                              hipStream_t stream) {
  const float* x = (const float*)d_in[0];    // [256,1024] f32
  const float* w = (const float*)d_in[1];    // [1024,1024] f32
  const float* b = (const float*)d_in[2];    // [1024] f32
  float* out = (float*)d_out;                // [256,1024] f32

  dim3 grid(ODIM / TILE_O, BDIM / TILE_B);   // (4, 128) = 512 blocks = 2/CU
  dim3 block(64, NW);                        // 512 threads = 8 waves
  stl_kernel<<<grid, block, 0, stream>>>(x, w, b, out);
}

// Round 11
// 92.856 us; speedup vs baseline: 1.0196x; 1.0141x over previous
//
#include <hip/hip_runtime.h>

// Problem dims (fixed by reference setup_inputs)
#define BDIM 256
#define IDIM 1024
#define ODIM 1024

#define NW 8                  // waves per block, each owns an i-eighth
#define OL 4                  // contiguous output columns per lane (dwordx4)
#define TILE_O (64 * OL)      // 256 outputs per block
#define TILE_B 2              // batch rows per thread
#define QLEN (IDIM / NW)      // 128 i per wave
#define CHUNK 4               // i per w-prefetch chunk (4 x dwordx4)
#define NCHUNK (QLEN / CHUNK) // 32 chunks

typedef float v2f __attribute__((ext_vector_type(2)));
typedef float v4f __attribute__((ext_vector_type(4)));

#if __has_builtin(__builtin_amdgcn_exp2f)
#define FAST_EXP2(v) __builtin_amdgcn_exp2f(v)
#else
#define FAST_EXP2(v) exp2f(v)
#endif

__global__ __launch_bounds__(512, 4)
void stl_kernel(const float* __restrict__ x,
                const float* __restrict__ w,
                const float* __restrict__ bias,
                float* __restrict__ out) {
  __shared__ float xs[TILE_B][IDIM];    // 8 KB: 2 x rows, prescaled by log2e
  __shared__ float ps[NW][16][68];      // ~34 KB: [wave][slot][lane]

  const int tx = threadIdx.x;           // 0..63 -> o-quad (lane)
  const int ty = threadIdx.y;           // 0..7  -> i-eighth (one wave each)
  const int tid = ty * 64 + tx;
  const int o0 = blockIdx.x * TILE_O;
  const int b0 = blockIdx.y * TILE_B;

  const float LOG2E = 1.4426950408889634f;  // folds 1/TEMPERATURE too

  // ---- Stage 2 x rows once (coalesced, prescaled). Barrier #1. ----
  {
    int row = tid >> 8;                 // 256 float4 per row, 512 total
    int col = tid & 255;
    float4 v = ((const float4*)(x + (size_t)(b0 + row) * IDIM))[col];
    v.x *= LOG2E; v.y *= LOG2E; v.z *= LOG2E; v.w *= LOG2E;
    ((float4*)(&xs[row][0]))[col] = v;
  }
  __syncthreads();

  const int qbase = ty * QLEN;
  // Lane owns 4 CONTIGUOUS columns o0+4*tx..+3 (one dwordx4 per i).
  const float* wp = w + (size_t)qbase * ODIM + o0 + 4 * tx;

  // Accumulators: [o-pair][batch row], pk over o.
  v2f an[2][TILE_B], ad[2][TILE_B];
#pragma unroll
  for (int s = 0; s < 2; ++s)
#pragma unroll
    for (int r = 0; r < TILE_B; ++r) { an[s][r] = (v2f){0.f, 0.f}; ad[s][r] = (v2f){0.f, 0.f}; }

  // w double buffer: 4 x dwordx4 per chunk.
  v4f wA[CHUNK], wB[CHUNK];

  // 1-step softwarepipeline state: produced (p,t) of the in-flight STEPQ.
  // Breaks the exp->fma dependency that serialized trans & main pipes.
  v2f pA[4], tA[4], pB[4], tB[4];

#define WLOADQ(dst, cc)                                                   \
  {                                                                       \
    const float* wq = wp + (size_t)((cc) * CHUNK) * ODIM;                 \
    _Pragma("unroll")                                                     \
    for (int u = 0; u < CHUNK; ++u)                                       \
      dst[u] = *(const v4f*)(wq + (size_t)u * ODIM);                      \
  }

#define LOQ(q) __builtin_shufflevector(q, q, 0, 1)
#define HIQ(q) __builtin_shufflevector(q, q, 2, 3)

  // PRODUCE: 4 pk_mul + 8 exp into (Pn, Tn). Literal ii only.
#define PROD(wc, xq0, xq1, ii, Pn, Tn)                                    \
  {                                                                       \
    v2f wlo = LOQ(wc[ii]), whi = HIQ(wc[ii]);                             \
    v2f x0 = __builtin_shufflevector(xq0, xq0, ii, ii);                   \
    v2f x1 = __builtin_shufflevector(xq1, xq1, ii, ii);                   \
    Pn[0] = x0 * wlo; Pn[1] = x0 * whi;                                   \
    Pn[2] = x1 * wlo; Pn[3] = x1 * whi;                                   \
    Tn[0].x = FAST_EXP2(__builtin_fabsf(Pn[0].x));                        \
    Tn[0].y = FAST_EXP2(__builtin_fabsf(Pn[0].y));                        \
    Tn[1].x = FAST_EXP2(__builtin_fabsf(Pn[1].x));                        \
    Tn[1].y = FAST_EXP2(__builtin_fabsf(Pn[1].y));                        \
    Tn[2].x = FAST_EXP2(__builtin_fabsf(Pn[2].x));                        \
    Tn[2].y = FAST_EXP2(__builtin_fabsf(Pn[2].y));                        \
    Tn[3].x = FAST_EXP2(__builtin_fabsf(Pn[3].x));                        \
    Tn[3].y = FAST_EXP2(__builtin_fabsf(Pn[3].y));                        \
  }

  // CONSUME the PREVIOUS step's (Pc, Tc): 8 pk ops, independent of the
  // exps just issued -> fills the main pipe under the trans drain.
#define CONS(Pc, Tc)                                                      \
  {                                                                       \
    an[0][0] += Pc[0] * Tc[0]; ad[0][0] += Tc[0];                         \
    an[1][0] += Pc[1] * Tc[1]; ad[1][0] += Tc[1];                         \
    an[0][1] += Pc[2] * Tc[2]; ad[0][1] += Tc[2];                         \
    an[1][1] += Pc[3] * Tc[3]; ad[1][1] += Tc[3];                         \
  }

  // Steady-state chunk: 4 steps, ping-pong A/B, pending batch enters in pB.
#define COMPUTEQ_PIPE(wc, cc)                                             \
  {                                                                       \
    const int jb = qbase + (cc) * CHUNK;                                  \
    v4f xq0 = *(const v4f*)(&xs[0][jb]);                                  \
    v4f xq1 = *(const v4f*)(&xs[1][jb]);                                  \
    PROD(wc, xq0, xq1, 0, pA, tA) CONS(pB, tB)                            \
    PROD(wc, xq0, xq1, 1, pB, tB) CONS(pA, tA)                            \
    PROD(wc, xq0, xq1, 2, pA, tA) CONS(pB, tB)                            \
    PROD(wc, xq0, xq1, 3, pB, tB) CONS(pA, tA)                            \
  }

  // ---- Main loop: depth-1 w prefetch + 1-step exp pipeline. ----
  WLOADQ(wA, 0)
  WLOADQ(wB, 1)
  // Peeled chunk 0 (prologue: step 0 produces only).
  {
    const int jb = qbase;
    v4f xq0 = *(const v4f*)(&xs[0][jb]);
    v4f xq1 = *(const v4f*)(&xs[1][jb]);
    PROD(wA, xq0, xq1, 0, pA, tA)
    PROD(wA, xq0, xq1, 1, pB, tB) CONS(pA, tA)
    PROD(wA, xq0, xq1, 2, pA, tA) CONS(pB, tB)
    PROD(wA, xq0, xq1, 3, pB, tB) CONS(pA, tA)
  }
  for (int c = 1; c + 1 < NCHUNK; c += 2) {   // c = 1,3,...,29
    WLOADQ(wA, c + 1)
    COMPUTEQ_PIPE(wB, c)
    WLOADQ(wB, (c + 2) & (NCHUNK - 1))
    COMPUTEQ_PIPE(wA, c + 1)
  }
  COMPUTEQ_PIPE(wB, NCHUNK - 1)               // chunk 31 (loaded in last iter)
  CONS(pB, tB)                                // drain the pipeline

  // ---- Cross-wave combine (barrier #2) ----
  // slots: b*8 + k (k=0..3 num for o=4tx+k), b*8+4+k den; [wave][slot][lane].
#pragma unroll
  for (int bq = 0; bq < TILE_B; ++bq) {
    ps[ty][bq * 8 + 0][tx] = an[0][bq].x;
    ps[ty][bq * 8 + 1][tx] = an[0][bq].y;
    ps[ty][bq * 8 + 2][tx] = an[1][bq].x;
    ps[ty][bq * 8 + 3][tx] = an[1][bq].y;
    ps[ty][bq * 8 + 4][tx] = ad[0][bq].x;
    ps[ty][bq * 8 + 5][tx] = ad[0][bq].y;
    ps[ty][bq * 8 + 6][tx] = ad[1][bq].x;
    ps[ty][bq * 8 + 7][tx] = ad[1][bq].y;
  }
  __syncthreads();

  // 512 outputs (2 b x 256 o); each thread takes one.
  {
    const int o_rel = tid & 255;         // 0..255
    const int bq = tid >> 8;             // 0/1
    const int t = o_rel >> 2;            // owning lane
    const int k = o_rel & 3;             // quad index
    float n = 0.f, d = 0.f;
#pragma unroll
    for (int wv = 0; wv < NW; ++wv) {
      n += ps[wv][bq * 8 + k][t];
      d += ps[wv][bq * 8 + 4 + k][t];
    }
    const float LN2 = 0.6931471805599453f;
    const float scale = (float)IDIM * LN2;    // undo log2e, apply n=IDIM
    const int o = o0 + o_rel;
    out[(size_t)(b0 + bq) * ODIM + o] = scale * n / d + bias[o];
  }
}

extern "C" void kernel_launch(void* const* d_in, const int* in_sizes, int n_in,
                              void* d_out, int out_size, void* d_ws, size_t ws_size,
                              hipStream_t stream) {
  const float* x = (const float*)d_in[0];    // [256,1024] f32
  const float* w = (const float*)d_in[1];    // [1024,1024] f32
  const float* b = (const float*)d_in[2];    // [1024] f32
  float* out = (float*)d_out;                // [256,1024] f32

  dim3 grid(ODIM / TILE_O, BDIM / TILE_B);   // (4, 128) = 512 blocks = 2/CU
  dim3 block(64, NW);                        // 512 threads = 8 waves
  stl_kernel<<<grid, block, 0, stream>>>(x, w, b, out);
}